// Round 9
// baseline (328.182 us; speedup 1.0000x reference)
//
#include <hip/hip_runtime.h>
#include <hip/hip_fp8.h>
#include <cstdint>

// ---------------------------------------------------------------------------
// GNN pipeline: corr-adjacency (bitmask) -> SAGEConv -> SAGPool -> SAGEConv ->
// SAGPool -> mean pool -> MLP head.
// R2-R20: see history.  R20 lesson: corr staging/conflict changes (2.06M ->
// 6.19M conflicts, occ 25->34%) left the merged kernel duration EXACTLY
// unchanged (64.5us) -> LDS conflicts are not on the critical path; the
// 64.5us ~= corr(28) + gemm1(36) because blocks dispatch in ID order and the
// two halves never co-reside (no overlap).  R21: ONE change — interleaved
// block-ID decode at 8-block granularity (9 corr-groups : 4 gemm-groups per
// 13), preserving both halves' &7 XCD alignment, so gemm's barrier stalls are
// filled by corr's MFMA work.  Everything else identical to R20.
// ---------------------------------------------------------------------------

typedef __bf16 bf16x8 __attribute__((ext_vector_type(8)));
typedef float  floatx4 __attribute__((ext_vector_type(4)));

#define MFMA_BF16(a, b, c) __builtin_amdgcn_mfma_f32_16x16x32_bf16((a), (b), (c), 0, 0, 0)
#define MFMA_FP8(a, b, c)  __builtin_amdgcn_mfma_f32_16x16x32_fp8_fp8((a), (b), (c), 0, 0, 0)

// async global -> LDS, 16 bytes per lane; LDS dest must be wave-uniform base
// (HW adds lane*16), global src is per-lane.
typedef __attribute__((address_space(1))) const void as1_cvoid;
typedef __attribute__((address_space(3))) void as3_void;
static __device__ __forceinline__ void gl16(const void* g, void* l) {
  __builtin_amdgcn_global_load_lds((as1_cvoid*)g, (as3_void*)l, 16, 0, 0);
}

static constexpr int BATCH = 64, NNODE = 1024, FIN = 195, FPAD = 224;
static constexpr int HD = 128, OD = 64, KP1 = 512, KP2 = 256;

// ---- workspace layout (bytes) ---------------------------------------------
static constexpr size_t OFF_GHI   = 0;          // x1g hi   [B*512*128] bf16
static constexpr size_t OFF_GLO   = 8388608;    // x1g lo
static constexpr size_t OFF_A1B   = 16777216;   // A1 bits  [B*512][8] u64
static constexpr size_t OFF_YR2   = 18874368;   // [B*512][128] f32
static constexpr size_t OFF_X2    = 35651584;   // [B*512][64]  f32
static constexpr size_t OFF_XHI   = 0;          // [B*N][224] bf16
static constexpr size_t OFF_XLO   = 29360128;
static constexpr size_t OFF_ABITS = 58720256;   // [B*N][64] u16 (= [B*N][16] u64)
static constexpr size_t OFF_X1    = 67108864;   // [B*N][128] f32
static constexpr size_t OFF_P1    = 100663296;
static constexpr size_t OFF_Q1    = OFF_P1 + 262144;
static constexpr size_t OFF_IDX1  = OFF_Q1 + 262144;
static constexpr size_t OFF_GATE1 = OFF_IDX1 + 131072;
static constexpr size_t OFF_P2    = OFF_GATE1 + 131072;
static constexpr size_t OFF_Q2    = OFF_P2 + 131072;
static constexpr size_t OFF_W1HI  = OFF_Q2 + 131072;     // [256][224] bf16
static constexpr size_t OFF_W1LO  = OFF_W1HI + 114688;
static constexpr size_t OFF_W2HI  = OFF_W1LO + 114688;   // [128][128] bf16
static constexpr size_t OFF_W2LO  = OFF_W2HI + 32768;
static constexpr size_t OFF_FC1T  = OFF_W2LO + 32768;    // [64][512] f32 = 128KB
static constexpr size_t OFF_FC2T  = OFF_FC1T + 131072;   // [512][256] f32 = 512KB
// FC2T ends at 102662144 < OFF_XHAT (102760448): no overlap.
static constexpr size_t OFF_XHAT  = 102760448;  // [B*N][224] fp8 (dead after corr)
static constexpr size_t OFF_YR1   = 102760448 + 16777216;  // [B*N][256] f32

static __device__ __forceinline__ unsigned char to_fp8(float v) {
  __hip_fp8_e4m3 q(v);
  return *(unsigned char*)&q;
}

// ---------------------------------------------------------------------------
// K0: prep (per-row normalize + split-bf16 + fp8 xhat) fused with weight pack
// and fc1/fc2 transposes for the coalesced head MLP.
__global__ __launch_bounds__(256) void prep_pack_kernel(
    const float* __restrict__ x, __bf16* __restrict__ xhi,
    __bf16* __restrict__ xlo, unsigned char* __restrict__ xhat8,
    const float* __restrict__ W1l, const float* __restrict__ W1r,
    __bf16* __restrict__ hi1, __bf16* __restrict__ lo1,
    const float* __restrict__ W2l, const float* __restrict__ W2r,
    __bf16* __restrict__ hi2, __bf16* __restrict__ lo2,
    const float* __restrict__ fc1w, float* __restrict__ fc1t,
    const float* __restrict__ fc2w, float* __restrict__ fc2t) {
  int bid = blockIdx.x;
  if (bid < 16384) {
    int row  = bid * 4 + (threadIdx.x >> 6);
    int lane = threadIdx.x & 63;
    const float* xr = x + (long)row * FIN;
    int k0 = lane * 4;
    float v[4];
#pragma unroll
    for (int i = 0; i < 4; ++i) v[i] = (k0 + i < FIN) ? xr[k0 + i] : 0.f;
    float s = v[0] + v[1] + v[2] + v[3];
#pragma unroll
    for (int o = 32; o; o >>= 1) s += __shfl_xor(s, o);
    float mean = s * (1.f / (float)FIN);
    float c[4], ss = 0.f;
#pragma unroll
    for (int i = 0; i < 4; ++i) {
      c[i] = (k0 + i < FIN) ? (v[i] - mean) : 0.f;
      ss += c[i] * c[i];
    }
#pragma unroll
    for (int o = 32; o; o >>= 1) ss += __shfl_xor(ss, o);
    float inv = rsqrtf(fmaxf(ss, 1e-12f));
    if (k0 < FPAD) {
      __bf16 hi4[4], lo4[4];
      unsigned char h8[4];
#pragma unroll
      for (int i = 0; i < 4; ++i) {
        float xv = (k0 + i < FIN) ? v[i] : 0.f;
        __bf16 h = (__bf16)xv;
        hi4[i] = h;
        lo4[i] = (__bf16)(xv - (float)h);
        h8[i] = to_fp8(c[i] * inv);
      }
      long base = (long)row * FPAD + k0;
      *(uint2*)&xhi[base] = *(const uint2*)hi4;
      *(uint2*)&xlo[base] = *(const uint2*)lo4;
      *(unsigned int*)&xhat8[base] = *(const unsigned int*)h8;
    }
  } else if (bid < 16384 + 224) {
    int idx = (bid - 16384) * 256 + threadIdx.x;  // 256*224
    int h = idx / FPAD, k = idx % FPAD;
    float v = 0.f;
    if (k < FIN) v = (h < HD) ? W1l[h * FIN + k] : W1r[(h - HD) * FIN + k];
    __bf16 a = (__bf16)v;
    hi1[idx] = a;
    lo1[idx] = (__bf16)(v - (float)a);
  } else if (bid < 16672) {
    int idx = (bid - 16384 - 224) * 256 + threadIdx.x;  // 128*128
    int h = idx / HD, k = idx % HD;
    float v = (h < OD) ? W2l[h * HD + k] : W2r[(h - OD) * HD + k];
    __bf16 a = (__bf16)v;
    hi2[idx] = a;
    lo2[idx] = (__bf16)(v - (float)a);
  } else if (bid < 16800) {
    // fc1T[j*512+o] = fc1_w[o*64+j]  (write-coalesced)
    int idx = (bid - 16672) * 256 + threadIdx.x;  // 0..32767
    int o = idx & 511, j = idx >> 9;
    fc1t[idx] = fc1w[o * 64 + j];
  } else {
    // fc2T[j*256+o] = fc2_w[o*512+j]  (write-coalesced)
    int idx = (bid - 16800) * 256 + threadIdx.x;  // 0..131071
    int o = idx & 255, j = idx >> 8;
    fc2t[idx] = fc2w[o * 512 + j];
  }
}

// ---------------------------------------------------------------------------
// K1+K2 merged + INTERLEAVED: corr bits (inline mirror transpose) + gemm1.
// Block decode (R21): u = bid>>3, r13 = u%13 — r13<9 -> corr group, else
// gemm group; bottom 3 bits pass through so both halves keep their original
// &7 XCD alignment.  Resident mix is ~9:4 corr:gemm at all times -> gemm's
// barrier stalls are filled by corr's MFMA work.
// corr [2304 blocks]: upper-triangular 128x128 pairs (36/batch), gl16 staging
//   into linear [128][32B] tiles, ballot -> bit pieces + in-register 16x16
//   bit-transpose for the mirrored (bj,bi) pieces.
// gemm1 [1024 blocks]: C = A @ B^T, 3-term split bf16, K=224, NCOL=2; R16
//   structure (single-buffer gl16 LDS, 2-barrier K-loop, XOR swizzle).
__global__ __launch_bounds__(256, 4) void corr_gemm1_kernel(
    const unsigned char* __restrict__ xhat8, unsigned short* __restrict__ Abits,
    const __bf16* __restrict__ Ahi, const __bf16* __restrict__ Alo,
    const __bf16* __restrict__ Bhi, const __bf16* __restrict__ Blo,
    float* __restrict__ C) {
  __shared__ __align__(16) char pool[32768];
  int bid = blockIdx.x;
  int t = threadIdx.x;
  int lane = t & 63, wave = t >> 6;
  int wi = (wave >> 1) * 64, wj = (wave & 1) * 64;
  int lr = lane & 15;
  // ---- interleaved decode (9 corr : 4 gemm per 13 groups of 8 blocks) ----
  int u = bid >> 3, low3 = bid & 7;
  int u13 = u / 13, r13 = u - u13 * 13;
  if (r13 < 9) {
    // ================= corr =================
    int cid = ((u13 * 9 + r13) << 3) | low3;   // [0, 2304), cid&7 == bid&7
    unsigned char* sI = (unsigned char*)pool;          // [128][32] = 4096B
    unsigned char* sJ = (unsigned char*)pool + 4096;   // [128][32] = 4096B
    int xcd = cid & 7;
    int m = cid >> 3;
    int b = xcd + ((m & 7) << 3);
    int rem = m >> 3, bi = 0;             // triangular decode -> (bi <= bj)
    while (rem >= 8 - bi) { rem -= 8 - bi; ++bi; }
    int bj = bi + rem;
    int i0 = bi * 128, j0 = bj * 128;
    const unsigned char* Xb = xhat8 + (long)b * NNODE * FPAD;
    int lk8 = (lane >> 4) * 8;            // byte offset of 8-elem fragment
    // staging: wave w stages rows [32w, 32w+32); lane l -> row 32w+(l>>1),
    // 16B chunk (l&1).  LDS byte = w*1024 + l*16  (linear [128][32]).
    int srow = (wave << 5) + (lane >> 1);
    int sck = (lane & 1) << 4;
    const char* gsI = (const char*)Xb + (long)(i0 + srow) * FPAD + sck;
    const char* gsJ = (const char*)Xb + (long)(j0 + srow) * FPAD + sck;
    char* ldI = (char*)sI + (wave << 10);
    char* ldJ = (char*)sJ + (wave << 10);
    floatx4 zero = {0.f, 0.f, 0.f, 0.f};
    floatx4 acc[4][4];
#pragma unroll
    for (int i = 0; i < 4; ++i)
#pragma unroll
      for (int j = 0; j < 4; ++j) acc[i][j] = zero;
    for (int kk = 0; kk < 7; ++kk) {
      __syncthreads();
      gl16(gsI, ldI);
      gl16(gsJ, ldJ);
      gsI += 32; gsJ += 32;
      __syncthreads();                    // vmcnt drained -> tiles ready
      long long af[4], bf[4];
#pragma unroll
      for (int tt = 0; tt < 4; ++tt) {
        af[tt] = *(const long long*)&sI[(wi + tt * 16 + lr) * 32 + lk8];
        bf[tt] = *(const long long*)&sJ[(wj + tt * 16 + lr) * 32 + lk8];
      }
#pragma unroll
      for (int ti = 0; ti < 4; ++ti)
#pragma unroll
        for (int tj = 0; tj < 4; ++tj)
          acc[ti][tj] = MFMA_FP8(af[ti], bf[tj], acc[ti][tj]);
    }
#pragma unroll
    for (int ti = 0; ti < 4; ++ti)
#pragma unroll
      for (int tj = 0; tj < 4; ++tj) {
        floatx4 a = acc[ti][tj];
        unsigned long long mr[4];
        mr[0] = __ballot(a[0] > 0.5f);
        mr[1] = __ballot(a[1] > 0.5f);
        mr[2] = __ballot(a[2] > 0.5f);
        mr[3] = __ballot(a[3] > 0.5f);
        if (lane < 16) {
          // upper piece: row = i0+wi+ti*16+lane, 16 cols at j0+wj+tj*16
          unsigned long long mm = mr[lane & 3];
          unsigned short piece = (unsigned short)(mm >> ((lane >> 2) * 16));
          int grow = i0 + wi + ti * 16 + lane;
          int gcol = (j0 + wj + tj * 16) >> 4;
          Abits[((long)b * NNODE + grow) * 64 + gcol] = piece;
          if (bi != bj) {
            // mirror piece: bit tp[tb] = original (row=tb, col=lane) of this
            // 16x16 tile; original bit lives in mr[tb&3] at bit (tb>>2)*16+lane.
            unsigned int tp = 0;
#pragma unroll
            for (int tb = 0; tb < 16; ++tb)
              tp |= (unsigned int)((mr[tb & 3] >> ((tb >> 2) * 16 + lane)) & 1ULL) << tb;
            int grow2 = j0 + wj + tj * 16 + lane;
            int gcol2 = (i0 + wi + ti * 16) >> 4;
            Abits[((long)b * NNODE + grow2) * 64 + gcol2] = (unsigned short)tp;
          }
        }
      }
  } else {
    // ================= gemm1 (K=224, NCOL=2) =================
    constexpr int K = 224;
    constexpr int ldc = 256;
    int gid = ((u13 * 4 + (r13 - 9)) << 3) | low3;  // [0, 1024), gid&7 == bid&7
    int xcd = gid & 7;               // pair (m, col0/1) shares gid mod 8
    int q = gid >> 3;
    int col = q & 1;
    int mrow = (xcd << 6) + (q >> 1);
    __bf16* sAh = (__bf16*)pool;                  // 8192B each
    __bf16* sAl = (__bf16*)(pool + 8192);
    __bf16* sBh = (__bf16*)(pool + 16384);
    __bf16* sBl = (__bf16*)(pool + 24576);
    long row0 = (long)mrow * 128;
    int col0 = col * 128;
    int lk2 = (lane >> 4) * 16;                   // byte offset of K-fragment
    int lk2s = lk2 ^ (((lr >> 1) & 3) << 4);      // swizzled read offset
    // staging: thread t owns LDS (row t>>2, slot t&3); fetch global slot
    // (t&3)^((row>>1)&3) so the linear DMA write lands swizzled data.
    int sr = t >> 2;
    int scb = (((t & 3) ^ ((sr >> 1) & 3)) << 4); // source byte offset in 64B row
    const char* gA0 = (const char*)Ahi + (row0 + sr) * (long)K * 2 + scb;
    const char* gA1 = (const char*)Alo + (row0 + sr) * (long)K * 2 + scb;
    const char* gB0 = (const char*)Bhi + (long)(col0 + sr) * K * 2 + scb;
    const char* gB1 = (const char*)Blo + (long)(col0 + sr) * K * 2 + scb;
    constexpr long rstep = 64L * K * 2;           // +64 rows, bytes
    char* lAh = (char*)sAh + (wave << 10);        // wave-uniform LDS bases
    char* lAl = (char*)sAl + (wave << 10);
    char* lBh = (char*)sBh + (wave << 10);
    char* lBl = (char*)sBl + (wave << 10);
    floatx4 zero = {0.f, 0.f, 0.f, 0.f};
    floatx4 acc[4][4];
#pragma unroll
    for (int i = 0; i < 4; ++i)
#pragma unroll
      for (int j = 0; j < 4; ++j) acc[i][j] = zero;
    for (int kk = 0; kk < (K >> 5); ++kk) {
      __syncthreads();                            // prev compute done
      gl16(gA0, lAh); gl16(gA0 + rstep, lAh + 4096);
      gl16(gA1, lAl); gl16(gA1 + rstep, lAl + 4096);
      gl16(gB0, lBh); gl16(gB0 + rstep, lBh + 4096);
      gl16(gB1, lBl); gl16(gB1 + rstep, lBl + 4096);
      gA0 += 64; gA1 += 64; gB0 += 64; gB1 += 64; // next 32-col K chunk
      __syncthreads();                            // vmcnt drained -> tiles ready
      bf16x8 bh[4], bl[4];
#pragma unroll
      for (int tj = 0; tj < 4; ++tj) {
        bh[tj] = *(const bf16x8*)((const char*)sBh + (wj + tj * 16 + lr) * 64 + lk2s);
        bl[tj] = *(const bf16x8*)((const char*)sBl + (wj + tj * 16 + lr) * 64 + lk2s);
      }
#pragma unroll
      for (int ti = 0; ti < 4; ++ti) {
        bf16x8 ah = *(const bf16x8*)((const char*)sAh + (wi + ti * 16 + lr) * 64 + lk2s);
        bf16x8 al = *(const bf16x8*)((const char*)sAl + (wi + ti * 16 + lr) * 64 + lk2s);
#pragma unroll
        for (int tj = 0; tj < 4; ++tj) acc[ti][tj] = MFMA_BF16(ah, bh[tj], acc[ti][tj]);
#pragma unroll
        for (int tj = 0; tj < 4; ++tj) acc[ti][tj] = MFMA_BF16(ah, bl[tj], acc[ti][tj]);
#pragma unroll
        for (int tj = 0; tj < 4; ++tj) acc[ti][tj] = MFMA_BF16(al, bh[tj], acc[ti][tj]);
      }
    }
#pragma unroll
    for (int ti = 0; ti < 4; ++ti)
#pragma unroll
      for (int tj = 0; tj < 4; ++tj)
#pragma unroll
        for (int rr = 0; rr < 4; ++rr) {
          long grow = row0 + wi + ti * 16 + (lane >> 4) * 4 + rr;
          int gcol = col0 + wj + tj * 16 + (lane & 15);
          C[grow * ldc + gcol] = acc[ti][tj][rr];
        }
  }
}

// ---------------------------------------------------------------------------
// K7: gemm2 — C = A @ B^T, 3-term split bf16, K=128, NCOL=1 (R16 structure).
template <int K, int NCOL>
__global__ __launch_bounds__(256, 3) void gemm_split_kernel(
    const __bf16* __restrict__ Ahi, const __bf16* __restrict__ Alo,
    const __bf16* __restrict__ Bhi, const __bf16* __restrict__ Blo,
    float* __restrict__ C) {
  constexpr int ldc = NCOL * 128;
  int bid = blockIdx.x;
  int mrow, col;
  if (NCOL == 2) {
    int xcd = bid & 7;
    int q = bid >> 3;
    col = q & 1;
    mrow = (xcd << 6) + (q >> 1);
  } else {
    mrow = bid;
    col = 0;
  }
  __shared__ __align__(16) __bf16 sAh[128 * 32];
  __shared__ __align__(16) __bf16 sAl[128 * 32];
  __shared__ __align__(16) __bf16 sBh[128 * 32];
  __shared__ __align__(16) __bf16 sBl[128 * 32];
  long row0 = (long)mrow * 128;
  int col0 = col * 128;
  int t = threadIdx.x;
  int lane = t & 63, wave = t >> 6;
  int wi = (wave >> 1) * 64, wj = (wave & 1) * 64;
  int lr = lane & 15, lk2 = (lane >> 4) * 16;   // byte offset of K-fragment
  int lk2s = lk2 ^ (((lr >> 1) & 3) << 4);      // swizzled read offset
  int sr = t >> 2;
  int scb = (((t & 3) ^ ((sr >> 1) & 3)) << 4); // source byte offset in 64B row
  const char* gA0 = (const char*)Ahi + (row0 + sr) * (long)K * 2 + scb;
  const char* gA1 = (const char*)Alo + (row0 + sr) * (long)K * 2 + scb;
  const char* gB0 = (const char*)Bhi + (long)(col0 + sr) * K * 2 + scb;
  const char* gB1 = (const char*)Blo + (long)(col0 + sr) * K * 2 + scb;
  constexpr long rstep = 64L * K * 2;           // +64 rows, bytes
  char* lAh = (char*)sAh + (wave << 10);        // wave-uniform LDS bases
  char* lAl = (char*)sAl + (wave << 10);
  char* lBh = (char*)sBh + (wave << 10);
  char* lBl = (char*)sBl + (wave << 10);
  floatx4 zero = {0.f, 0.f, 0.f, 0.f};
  floatx4 acc[4][4];
#pragma unroll
  for (int i = 0; i < 4; ++i)
#pragma unroll
    for (int j = 0; j < 4; ++j) acc[i][j] = zero;
  for (int kk = 0; kk < (K >> 5); ++kk) {
    __syncthreads();                            // prev compute done
    gl16(gA0, lAh); gl16(gA0 + rstep, lAh + 4096);
    gl16(gA1, lAl); gl16(gA1 + rstep, lAl + 4096);
    gl16(gB0, lBh); gl16(gB0 + rstep, lBh + 4096);
    gl16(gB1, lBl); gl16(gB1 + rstep, lBl + 4096);
    gA0 += 64; gA1 += 64; gB0 += 64; gB1 += 64; // next 32-col K chunk
    __syncthreads();                            // vmcnt drained -> tiles ready
    bf16x8 bh[4], bl[4];
#pragma unroll
    for (int tj = 0; tj < 4; ++tj) {
      bh[tj] = *(const bf16x8*)((const char*)sBh + (wj + tj * 16 + lr) * 64 + lk2s);
      bl[tj] = *(const bf16x8*)((const char*)sBl + (wj + tj * 16 + lr) * 64 + lk2s);
    }
#pragma unroll
    for (int ti = 0; ti < 4; ++ti) {
      bf16x8 ah = *(const bf16x8*)((const char*)sAh + (wi + ti * 16 + lr) * 64 + lk2s);
      bf16x8 al = *(const bf16x8*)((const char*)sAl + (wi + ti * 16 + lr) * 64 + lk2s);
#pragma unroll
      for (int tj = 0; tj < 4; ++tj) acc[ti][tj] = MFMA_BF16(ah, bh[tj], acc[ti][tj]);
#pragma unroll
      for (int tj = 0; tj < 4; ++tj) acc[ti][tj] = MFMA_BF16(ah, bl[tj], acc[ti][tj]);
#pragma unroll
      for (int tj = 0; tj < 4; ++tj) acc[ti][tj] = MFMA_BF16(al, bh[tj], acc[ti][tj]);
    }
  }
#pragma unroll
  for (int ti = 0; ti < 4; ++ti)
#pragma unroll
    for (int tj = 0; tj < 4; ++tj)
#pragma unroll
      for (int rr = 0; rr < 4; ++rr) {
        long grow = row0 + wi + ti * 16 + (lane >> 4) * 4 + rr;
        int gcol = col0 + wj + tj * 16 + (lane & 15);
        C[grow * ldc + gcol] = acc[ti][tj][rr];
      }
}

// ---------------------------------------------------------------------------
// K3: sage1, float4 form (R12).  8 nodes per 256-thread block; 32 lanes per
// node, each lane owns 4 consecutive h (float4 loads of YR1).
__global__ __launch_bounds__(256) void sage1_kernel(
    const unsigned int* __restrict__ Abits32, const float* __restrict__ YR1,
    const float* __restrict__ b1l, const float* __restrict__ Wrel,
    const float* __restrict__ Wroot, float* __restrict__ x1,
    float* __restrict__ p1, float* __restrict__ q1) {
  int g = threadIdx.x >> 5;          // 8 node-groups of 32 lanes
  int lane = threadIdx.x & 31;
  int node = blockIdx.x * 8 + g;     // b*1024+n
  int b = node >> 10, nloc = node & 1023;
  __shared__ int list[8][1024];
  __shared__ int s_deg[8];
  {
    unsigned int word = Abits32[(long)node * 32 + lane];
    int cnt = __popc(word);
    int off = cnt;
#pragma unroll
    for (int o = 1; o < 32; o <<= 1) {
      int v = __shfl_up(off, o, 32);
      if (lane >= o) off += v;
    }
    off -= cnt;  // exclusive prefix (ascending word order -> ordered list)
    if (lane == 31) s_deg[g] = off + cnt;
    int basei = lane * 32;
    while (word) {
      int t = __ffs(word) - 1;
      word &= word - 1;
      list[g][off++] = basei + t;
    }
  }
  __syncthreads();
  int deg = s_deg[g];
  const float4* Y4 = (const float4*)(YR1 + (long)(b << 10) * 256);  // 64 f4/row
  float4 a4 = {0.f, 0.f, 0.f, 0.f};
  for (int d = 0; d < deg; ++d) {
    float4 y = Y4[(long)list[g][d] * 64 + lane];
    a4.x += y.x; a4.y += y.y; a4.z += y.z; a4.w += y.w;
  }
  float4 R = Y4[(long)nloc * 64 + 32 + lane];
  float inv = 1.f / (float)(deg < 1 ? 1 : deg);
  float4 bl = ((const float4*)b1l)[lane];
  float4 v;
  v.x = fmaxf(a4.x * inv + bl.x + R.x, 0.f);
  v.y = fmaxf(a4.y * inv + bl.y + R.y, 0.f);
  v.z = fmaxf(a4.z * inv + bl.z + R.z, 0.f);
  v.w = fmaxf(a4.w * inv + bl.w + R.w, 0.f);
  ((float4*)x1)[(long)node * 32 + lane] = v;
  float4 wr = ((const float4*)Wrel)[lane];
  float4 wq = ((const float4*)Wroot)[lane];
  float pv = v.x * wr.x + v.y * wr.y + v.z * wr.z + v.w * wr.w;
  float qv = v.x * wq.x + v.y * wq.y + v.z * wq.z + v.w * wq.w;
#pragma unroll
  for (int o = 16; o; o >>= 1) {
    pv += __shfl_xor(pv, o, 32);
    qv += __shfl_xor(qv, o, 32);
  }
  if (lane == 0) { p1[node] = pv; q1[node] = qv; }
}

// ---------------------------------------------------------------------------
// K4+K5 fused: per-batch score (thread-per-row, sparse while-gather — cheap
// since deg~1 on this data) + radix top-k selection.
__global__ void scoretopk_kernel(const unsigned int* __restrict__ bits32,
                                 const float* __restrict__ p,
                                 const float* __restrict__ q,
                                 const float* __restrict__ brel,
                                 int* __restrict__ idx_out,
                                 float* __restrict__ gate_out,
                                 int nwords, int rpb_shift, int k) {
  int b = blockIdx.x, tid = threadIdx.x;
  int row = (b << rpb_shift) + tid;
  const unsigned int* wptr = bits32 + (long)row * nwords;
  const float* pb = p + ((long)b << rpb_shift);
  float s = q[row] + brel[0];
  for (int w = 0; w < nwords; ++w) {
    unsigned int word = wptr[w];
    while (word) {
      int t = __ffs(word) - 1;
      word &= word - 1;
      s += pb[w * 32 + t];
    }
  }
  unsigned int fb = __float_as_uint(s);
  unsigned int key = (fb & 0x80000000u) ? ~fb : (fb | 0x80000000u);
  __shared__ int hist[256];
  __shared__ unsigned int sh_prefix;
  __shared__ int sh_target, cnt_gt, cnt_eq, outpos;
  if (tid == 0) { sh_prefix = 0; sh_target = k; cnt_gt = 0; cnt_eq = 0; outpos = 0; }
  for (int shift = 24; shift >= 0; shift -= 8) {
    if (tid < 256) hist[tid] = 0;
    __syncthreads();
    unsigned int prefix = sh_prefix;
    bool inset = (shift == 24) || ((key >> (shift + 8)) == (prefix >> (shift + 8)));
    if (inset) atomicAdd(&hist[(key >> shift) & 255], 1);
    __syncthreads();
    if (tid < 64) {
      int lane = tid;
      int bb0 = hist[255 - 4 * lane];
      int bb1 = hist[254 - 4 * lane];
      int bb2 = hist[253 - 4 * lane];
      int bb3 = hist[252 - 4 * lane];
      int c0 = bb0, c1 = c0 + bb1, c2 = c1 + bb2, c3 = c2 + bb3;
      int incl = c3;
#pragma unroll
      for (int o = 1; o < 64; o <<= 1) {
        int v = __shfl_up(incl, o);
        if (lane >= o) incl += v;
      }
      int excl = incl - c3;
      int target = sh_target;  // read before any lane writes (lockstep)
      int cum[4] = {excl + c0, excl + c1, excl + c2, excl + c3};
      int prev = excl;
#pragma unroll
      for (int i = 0; i < 4; ++i) {
        if (cum[i] >= target && prev < target) {
          int bin = 255 - (4 * lane + i);
          sh_prefix = prefix | ((unsigned int)bin << shift);
          sh_target = target - prev;
        }
        prev = cum[i];
      }
    }
    __syncthreads();
  }
  unsigned int T = sh_prefix;
  if (key > T) atomicAdd(&cnt_gt, 1);
  __syncthreads();
  int E = k - cnt_gt;
  bool sel = (key > T);
  if (!sel && key == T) sel = (atomicAdd(&cnt_eq, 1) < E);
  if (sel) {
    int posn = atomicAdd(&outpos, 1);
    idx_out[b * k + posn] = tid;
    gate_out[b * k + posn] = tanhf(s);
  }
}

// K6: fused gather: x1 rows * tanh gate -> split bf16, and A1 bit gather.
__global__ __launch_bounds__(256) void gather_kernel(
    const float* __restrict__ x1, const int* __restrict__ idx,
    const float* __restrict__ gate, __bf16* __restrict__ ghi,
    __bf16* __restrict__ glo, const unsigned int* __restrict__ Abits32,
    unsigned long long* __restrict__ A1bits) {
  int bid = blockIdx.x;
  if (bid < 16384) {
    long e = (long)bid * 256 + threadIdx.x;  // B*512*128
    int h = (int)(e & 127);
    int i = (int)((e >> 7) & 511);
    int b = (int)(e >> 16);
    int srow = idx[(b << 9) + i];
    float v = x1[((long)(b << 10) + srow) * 128 + h] * gate[(b << 9) + i];
    __bf16 a = (__bf16)v;
    ghi[e] = a;
    glo[e] = (__bf16)(v - (float)a);
  } else {
    int gi = (bid - 16384) * 4 + (threadIdx.x >> 6);  // b*512+i
    int lane = threadIdx.x & 63;
    int b = gi >> 9;
    int srow = idx[gi];
    const unsigned int* src = Abits32 + ((long)(b << 10) + srow) * 32;
    const int* idxb = idx + (b << 9);
#pragma unroll
    for (int t = 0; t < 8; ++t) {
      int cj = idxb[t * 64 + lane];
      int bit = (src[cj >> 5] >> (cj & 31)) & 1;
      unsigned long long m = __ballot(bit);
      if (lane == 0) A1bits[(long)gi * 8 + t] = m;
    }
  }
}

// K8: sage2, float4 form (R12).  16 nodes per 256-thread block; 16 lanes per
// node, each lane owns 4 consecutive h.
__global__ __launch_bounds__(256) void sage2_kernel(
    const unsigned int* __restrict__ A1b32, const float* __restrict__ YR2,
    const float* __restrict__ b2l, const float* __restrict__ Wrel,
    const float* __restrict__ Wroot, float* __restrict__ x2,
    float* __restrict__ p2, float* __restrict__ q2) {
  int g = threadIdx.x >> 4;          // 16 node-groups of 16 lanes
  int lane = threadIdx.x & 15;
  int row = blockIdx.x * 16 + g;     // b*512+i
  int b = row >> 9, iloc = row & 511;
  __shared__ int list[16][512];
  __shared__ int s_deg[16];
  {
    unsigned int word = A1b32[(long)row * 16 + lane];
    int cnt = __popc(word);
    int off = cnt;
#pragma unroll
    for (int o = 1; o < 16; o <<= 1) {
      int v = __shfl_up(off, o, 16);
      if (lane >= o) off += v;
    }
    off -= cnt;
    if (lane == 15) s_deg[g] = off + cnt;
    int basei = lane * 32;
    while (word) {
      int t = __ffs(word) - 1;
      word &= word - 1;
      list[g][off++] = basei + t;
    }
  }
  __syncthreads();
  int deg = s_deg[g];
  const float4* Y4 = (const float4*)(YR2 + (long)(b << 9) * 128);  // 32 f4/row
  float4 a4 = {0.f, 0.f, 0.f, 0.f};
  for (int d = 0; d < deg; ++d) {
    float4 y = Y4[(long)list[g][d] * 32 + lane];
    a4.x += y.x; a4.y += y.y; a4.z += y.z; a4.w += y.w;
  }
  float4 R = Y4[(long)iloc * 32 + 16 + lane];
  float inv = 1.f / (float)(deg < 1 ? 1 : deg);
  float4 bl = ((const float4*)b2l)[lane];
  float4 v;
  v.x = fmaxf(a4.x * inv + bl.x + R.x, 0.f);
  v.y = fmaxf(a4.y * inv + bl.y + R.y, 0.f);
  v.z = fmaxf(a4.z * inv + bl.z + R.z, 0.f);
  v.w = fmaxf(a4.w * inv + bl.w + R.w, 0.f);
  ((float4*)x2)[(long)row * 16 + lane] = v;
  float4 wr = ((const float4*)Wrel)[lane];
  float4 wq = ((const float4*)Wroot)[lane];
  float pv = v.x * wr.x + v.y * wr.y + v.z * wr.z + v.w * wr.w;
  float qv = v.x * wq.x + v.y * wq.y + v.z * wq.z + v.w * wq.w;
#pragma unroll
  for (int o = 8; o; o >>= 1) {
    pv += __shfl_xor(pv, o, 16);
    qv += __shfl_xor(qv, o, 16);
  }
  if (lane == 0) { p2[row] = pv; q2[row] = qv; }
}

// ---------------------------------------------------------------------------
// K9+K10+K11 fused: per-batch score2 + topk2 (idx/gate in LDS) + MLP head.
// Score = sparse while-gather (R16 form); MLP per-thread with TRANSPOSED
// weights (fc1T[j][o], fc2T[j][o]) -> coalesced lane access (R18).
__global__ __launch_bounds__(512) void scoretopk_head_kernel(
    const unsigned int* __restrict__ A1b32, const float* __restrict__ p2,
    const float* __restrict__ q2, const float* __restrict__ brel,
    const float* __restrict__ x2, const float* __restrict__ fc1t,
    const float* __restrict__ fc1_b, const float* __restrict__ g1,
    const float* __restrict__ bb1, const float* __restrict__ m1,
    const float* __restrict__ v1, const float* __restrict__ fc2t,
    const float* __restrict__ fc2_b, const float* __restrict__ g2,
    const float* __restrict__ bb2, const float* __restrict__ m2,
    const float* __restrict__ v2, const float* __restrict__ fc3_w,
    const float* __restrict__ fc3_b, float* __restrict__ out) {
  int b = blockIdx.x, tid = threadIdx.x;
  // ---- score (thread-per-row, 512 rows, 16 words; sparse gather) ----
  int row = (b << 9) + tid;
  const unsigned int* wptr = A1b32 + (long)row * 16;
  const float* pb = p2 + ((long)b << 9);
  float s = q2[row] + brel[0];
  for (int w = 0; w < 16; ++w) {
    unsigned int word = wptr[w];
    while (word) {
      int t = __ffs(word) - 1;
      word &= word - 1;
      s += pb[w * 32 + t];
    }
  }
  // ---- top-256 radix select into LDS ----
  constexpr int k = KP2;
  unsigned int fb = __float_as_uint(s);
  unsigned int key = (fb & 0x80000000u) ? ~fb : (fb | 0x80000000u);
  __shared__ int hist[256];
  __shared__ int idx2s[256];
  __shared__ float gate2s[256];
  __shared__ unsigned int sh_prefix;
  __shared__ int sh_target, cnt_gt, cnt_eq, outpos;
  if (tid == 0) { sh_prefix = 0; sh_target = k; cnt_gt = 0; cnt_eq = 0; outpos = 0; }
  for (int shift = 24; shift >= 0; shift -= 8) {
    if (tid < 256) hist[tid] = 0;
    __syncthreads();
    unsigned int prefix = sh_prefix;
    bool inset = (shift == 24) || ((key >> (shift + 8)) == (prefix >> (shift + 8)));
    if (inset) atomicAdd(&hist[(key >> shift) & 255], 1);
    __syncthreads();
    if (tid < 64) {
      int lane = tid;
      int bb0 = hist[255 - 4 * lane];
      int bb1 = hist[254 - 4 * lane];
      int bb2 = hist[253 - 4 * lane];
      int bb3 = hist[252 - 4 * lane];
      int c0 = bb0, c1 = c0 + bb1, c2 = c1 + bb2, c3 = c2 + bb3;
      int incl = c3;
#pragma unroll
      for (int o = 1; o < 64; o <<= 1) {
        int v = __shfl_up(incl, o);
        if (lane >= o) incl += v;
      }
      int excl = incl - c3;
      int target = sh_target;
      int cum[4] = {excl + c0, excl + c1, excl + c2, excl + c3};
      int prev = excl;
#pragma unroll
      for (int i = 0; i < 4; ++i) {
        if (cum[i] >= target && prev < target) {
          int bin = 255 - (4 * lane + i);
          sh_prefix = prefix | ((unsigned int)bin << shift);
          sh_target = target - prev;
        }
        prev = cum[i];
      }
    }
    __syncthreads();
  }
  unsigned int T = sh_prefix;
  if (key > T) atomicAdd(&cnt_gt, 1);
  __syncthreads();
  int E = k - cnt_gt;
  bool sel = (key > T);
  if (!sel && key == T) sel = (atomicAdd(&cnt_eq, 1) < E);
  if (sel) {
    int posn = atomicAdd(&outpos, 1);
    idx2s[posn] = tid;
    gate2s[posn] = tanhf(s);
  }
  __syncthreads();
  // ---- head: mean pool over selected + MLP (transposed, coalesced) ----
  __shared__ float part[8][64];
  __shared__ float pooled[64];
  __shared__ float h1[512];
  __shared__ float h2[256];
  __shared__ float zz[2];
  int h = tid & 63, grp = tid >> 6;
  float sp = 0.f;
  for (int i = grp * 32; i < grp * 32 + 32; ++i) {
    int si = idx2s[i];
    sp += x2[((long)(b << 9) + si) * 64 + h] * gate2s[i];
  }
  part[grp][h] = sp;
  __syncthreads();
  if (tid < 64) {
    float t = 0.f;
#pragma unroll
    for (int g = 0; g < 8; ++g) t += part[g][tid];
    pooled[tid] = t * (1.f / 256.f);
  }
  __syncthreads();
  {
    // fc1: out o = tid (512); fc1T[j*512+o] -> lane-consecutive (coalesced)
    float z = fc1_b[tid];
#pragma unroll 8
    for (int j = 0; j < 64; ++j) z += pooled[j] * fc1t[j * 512 + tid];
    z = fmaxf(z, 0.f);
    h1[tid] = g1[tid] * (z - m1[tid]) * rsqrtf(v1[tid] + 1e-5f) + bb1[tid];
  }
  __syncthreads();
  if (tid < 256) {
    // fc2: out o = tid (256); fc2T[j*256+o] -> lane-consecutive (coalesced)
    float z = fc2_b[tid];
#pragma unroll 8
    for (int j = 0; j < 512; ++j) z += h1[j] * fc2t[j * 256 + tid];
    z = fmaxf(z, 0.f);
    h2[tid] = g2[tid] * (z - m2[tid]) * rsqrtf(v2[tid] + 1e-5f) + bb2[tid];
  }
  __syncthreads();
  if (tid < 2) {
    float z = fc3_b[tid];
    for (int j = 0; j < 256; ++j) z += h2[j] * fc3_w[tid * 256 + j];
    zz[tid] = z;
  }
  __syncthreads();
  if (tid == 0) {
    float mx = fmaxf(zz[0], zz[1]);
    float e0 = expf(zz[0] - mx), e1 = expf(zz[1] - mx);
    float inv = 1.f / (e0 + e1);
    out[b * 2 + 0] = e0 * inv;
    out[b * 2 + 1] = e1 * inv;
  }
}

// ---------------------------------------------------------------------------
extern "C" void kernel_launch(void* const* d_in, const int* in_sizes, int n_in,
                              void* d_out, int out_size, void* d_ws, size_t ws_size,
                              hipStream_t stream) {
  (void)in_sizes; (void)n_in; (void)out_size; (void)ws_size;
  const float* input   = (const float*)d_in[0];
  const float* W1l     = (const float*)d_in[1];
  const float* b1l     = (const float*)d_in[2];
  const float* W1r     = (const float*)d_in[3];
  const float* Wp1_rel = (const float*)d_in[4];
  const float* bp1_rel = (const float*)d_in[5];
  const float* Wp1_root= (const float*)d_in[6];
  const float* W2l     = (const float*)d_in[7];
  const float* b2l     = (const float*)d_in[8];
  const float* W2r     = (const float*)d_in[9];
  const float* Wp2_rel = (const float*)d_in[10];
  const float* bp2_rel = (const float*)d_in[11];
  const float* Wp2_root= (const float*)d_in[12];
  const float* fc1_w   = (const float*)d_in[13];
  const float* fc1_b   = (const float*)d_in[14];
  const float* bn1_g   = (const float*)d_in[15];
  const float* bn1_b   = (const float*)d_in[16];
  const float* bn1_m   = (const float*)d_in[17];
  const float* bn1_v   = (const float*)d_in[18];
  const float* fc2_w   = (const float*)d_in[19];
  const float* fc2_b   = (const float*)d_in[20];
  const float* bn2_g   = (const float*)d_in[21];
  const float* bn2_b   = (const float*)d_in[22];
  const float* bn2_m   = (const float*)d_in[23];
  const float* bn2_v   = (const float*)d_in[24];
  const float* fc3_w   = (const float*)d_in[25];
  const float* fc3_b   = (const float*)d_in[26];

  char* ws = (char*)d_ws;
  __bf16* xhi   = (__bf16*)(ws + OFF_XHI);
  __bf16* xlo   = (__bf16*)(ws + OFF_XLO);
  unsigned char* xhat8 = (unsigned char*)(ws + OFF_XHAT);
  unsigned short* Abits = (unsigned short*)(ws + OFF_ABITS);
  const unsigned int* Abits32 = (const unsigned int*)(ws + OFF_ABITS);
  float* YR1    = (float*)(ws + OFF_YR1);
  float* x1     = (float*)(ws + OFF_X1);
  float* p1     = (float*)(ws + OFF_P1);
  float* q1     = (float*)(ws + OFF_Q1);
  int*   idx1   = (int*)(ws + OFF_IDX1);
  float* gate1  = (float*)(ws + OFF_GATE1);
  float* p2     = (float*)(ws + OFF_P2);
  float* q2     = (float*)(ws + OFF_Q2);
  __bf16* w1hi  = (__bf16*)(ws + OFF_W1HI);
  __bf16* w1lo  = (__bf16*)(ws + OFF_W1LO);
  __bf16* w2hi  = (__bf16*)(ws + OFF_W2HI);
  __bf16* w2lo  = (__bf16*)(ws + OFF_W2LO);
  float* fc1t   = (float*)(ws + OFF_FC1T);
  float* fc2t   = (float*)(ws + OFF_FC2T);
  __bf16* ghi   = (__bf16*)(ws + OFF_GHI);
  __bf16* glo   = (__bf16*)(ws + OFF_GLO);
  unsigned long long* A1bits = (unsigned long long*)(ws + OFF_A1B);
  const unsigned int* A1b32  = (const unsigned int*)(ws + OFF_A1B);
  float* YR2    = (float*)(ws + OFF_YR2);
  float* x2     = (float*)(ws + OFF_X2);
  float* out    = (float*)d_out;

  prep_pack_kernel<<<17312, 256, 0, stream>>>(input, xhi, xlo, xhat8,
                                              W1l, W1r, w1hi, w1lo,
                                              W2l, W2r, w2hi, w2lo,
                                              fc1_w, fc1t, fc2_w, fc2t);
  // merged + interleaved: 2304 corr + 1024 gemm1 blocks (9:4 per 13 groups)
  corr_gemm1_kernel<<<3328, 256, 0, stream>>>(xhat8, Abits,
                                              xhi, xlo, w1hi, w1lo, YR1);
  sage1_kernel<<<8192, 256, 0, stream>>>(Abits32, YR1, b1l, Wp1_rel, Wp1_root, x1, p1, q1);
  scoretopk_kernel<<<64, 1024, 0, stream>>>(Abits32, p1, q1, bp1_rel, idx1, gate1,
                                            32, 10, KP1);
  gather_kernel<<<24576, 256, 0, stream>>>(x1, idx1, gate1, ghi, glo, Abits32, A1bits);
  gemm_split_kernel<128, 1><<<256, 256, 0, stream>>>(
      ghi, glo, w2hi, w2lo, YR2);
  sage2_kernel<<<2048, 256, 0, stream>>>(A1b32, YR2, b2l, Wp2_rel, Wp2_root, x2, p2, q2);
  scoretopk_head_kernel<<<64, 512, 0, stream>>>(A1b32, p2, q2, bp2_rel, x2,
                                                fc1t, fc1_b, bn1_g, bn1_b, bn1_m, bn1_v,
                                                fc2t, fc2_b, bn2_g, bn2_b, bn2_m, bn2_v,
                                                fc3_w, fc3_b, out);
}

// Round 10
// 320.734 us; speedup vs baseline: 1.0232x; 1.0232x over previous
//
#include <hip/hip_runtime.h>
#include <hip/hip_fp8.h>
#include <cstdint>

// ---------------------------------------------------------------------------
// GNN pipeline: corr-adjacency (bitmask) -> SAGEConv -> SAGPool -> SAGEConv ->
// SAGPool -> mean pool -> MLP head.
// R2-R21: see history.  3-point experiment on merged corr_gemm1: R19 uint4
// sequential 64.9us; R20 DMA staging 64.5us (staging mechanics irrelevant);
// R21 interleaved 66us + FETCH +9MB (co-residency hurts L2 locality).  The
// 64.5 = corr(28)+gemm1(36) serial because each half's 2-barrier K-loop
// serializes load->compute INTERNALLY.  R22: R19 base (proven 322.4) + corr
// DOUBLE-BUFFER — dbuf costs only +12KB (24.5KB < 32KB pool, occupancy
// unchanged — the reason R15's gemm dbuf failed is absent here): load(k+1)
// into regs, MFMA(k), write regs->buf^1, ONE barrier/iter (7 vs 14 barriers).
// ---------------------------------------------------------------------------

typedef __bf16 bf16x8 __attribute__((ext_vector_type(8)));
typedef float  floatx4 __attribute__((ext_vector_type(4)));

#define MFMA_BF16(a, b, c) __builtin_amdgcn_mfma_f32_16x16x32_bf16((a), (b), (c), 0, 0, 0)
#define MFMA_FP8(a, b, c)  __builtin_amdgcn_mfma_f32_16x16x32_fp8_fp8((a), (b), (c), 0, 0, 0)

// async global -> LDS, 16 bytes per lane; LDS dest must be wave-uniform base
// (HW adds lane*16), global src is per-lane.
typedef __attribute__((address_space(1))) const void as1_cvoid;
typedef __attribute__((address_space(3))) void as3_void;
static __device__ __forceinline__ void gl16(const void* g, void* l) {
  __builtin_amdgcn_global_load_lds((as1_cvoid*)g, (as3_void*)l, 16, 0, 0);
}

static constexpr int BATCH = 64, NNODE = 1024, FIN = 195, FPAD = 224;
static constexpr int HD = 128, OD = 64, KP1 = 512, KP2 = 256;

// ---- workspace layout (bytes) ---------------------------------------------
static constexpr size_t OFF_GHI   = 0;          // x1g hi   [B*512*128] bf16
static constexpr size_t OFF_GLO   = 8388608;    // x1g lo
static constexpr size_t OFF_A1B   = 16777216;   // A1 bits  [B*512][8] u64
static constexpr size_t OFF_YR2   = 18874368;   // [B*512][128] f32
static constexpr size_t OFF_X2    = 35651584;   // [B*512][64]  f32
static constexpr size_t OFF_XHI   = 0;          // [B*N][224] bf16
static constexpr size_t OFF_XLO   = 29360128;
static constexpr size_t OFF_ABITS = 58720256;   // [B*N][64] u16 (= [B*N][16] u64)
static constexpr size_t OFF_X1    = 67108864;   // [B*N][128] f32
static constexpr size_t OFF_P1    = 100663296;
static constexpr size_t OFF_Q1    = OFF_P1 + 262144;
static constexpr size_t OFF_IDX1  = OFF_Q1 + 262144;
static constexpr size_t OFF_GATE1 = OFF_IDX1 + 131072;
static constexpr size_t OFF_P2    = OFF_GATE1 + 131072;
static constexpr size_t OFF_Q2    = OFF_P2 + 131072;
static constexpr size_t OFF_W1HI  = OFF_Q2 + 131072;     // [256][224] bf16
static constexpr size_t OFF_W1LO  = OFF_W1HI + 114688;
static constexpr size_t OFF_W2HI  = OFF_W1LO + 114688;   // [128][128] bf16
static constexpr size_t OFF_W2LO  = OFF_W2HI + 32768;
static constexpr size_t OFF_FC1T  = OFF_W2LO + 32768;    // [64][512] f32 = 128KB
static constexpr size_t OFF_FC2T  = OFF_FC1T + 131072;   // [512][256] f32 = 512KB
// FC2T ends at 102662144 < OFF_XHAT (102760448): no overlap.
static constexpr size_t OFF_XHAT  = 102760448;  // [B*N][224] fp8 (dead after corr)
static constexpr size_t OFF_YR1   = 102760448 + 16777216;  // [B*N][256] f32

static __device__ __forceinline__ unsigned char to_fp8(float v) {
  __hip_fp8_e4m3 q(v);
  return *(unsigned char*)&q;
}

// ---------------------------------------------------------------------------
// K0: prep (per-row normalize + split-bf16 + fp8 xhat) fused with weight pack
// and fc1/fc2 transposes for the coalesced head MLP.
__global__ __launch_bounds__(256) void prep_pack_kernel(
    const float* __restrict__ x, __bf16* __restrict__ xhi,
    __bf16* __restrict__ xlo, unsigned char* __restrict__ xhat8,
    const float* __restrict__ W1l, const float* __restrict__ W1r,
    __bf16* __restrict__ hi1, __bf16* __restrict__ lo1,
    const float* __restrict__ W2l, const float* __restrict__ W2r,
    __bf16* __restrict__ hi2, __bf16* __restrict__ lo2,
    const float* __restrict__ fc1w, float* __restrict__ fc1t,
    const float* __restrict__ fc2w, float* __restrict__ fc2t) {
  int bid = blockIdx.x;
  if (bid < 16384) {
    int row  = bid * 4 + (threadIdx.x >> 6);
    int lane = threadIdx.x & 63;
    const float* xr = x + (long)row * FIN;
    int k0 = lane * 4;
    float v[4];
#pragma unroll
    for (int i = 0; i < 4; ++i) v[i] = (k0 + i < FIN) ? xr[k0 + i] : 0.f;
    float s = v[0] + v[1] + v[2] + v[3];
#pragma unroll
    for (int o = 32; o; o >>= 1) s += __shfl_xor(s, o);
    float mean = s * (1.f / (float)FIN);
    float c[4], ss = 0.f;
#pragma unroll
    for (int i = 0; i < 4; ++i) {
      c[i] = (k0 + i < FIN) ? (v[i] - mean) : 0.f;
      ss += c[i] * c[i];
    }
#pragma unroll
    for (int o = 32; o; o >>= 1) ss += __shfl_xor(ss, o);
    float inv = rsqrtf(fmaxf(ss, 1e-12f));
    if (k0 < FPAD) {
      __bf16 hi4[4], lo4[4];
      unsigned char h8[4];
#pragma unroll
      for (int i = 0; i < 4; ++i) {
        float xv = (k0 + i < FIN) ? v[i] : 0.f;
        __bf16 h = (__bf16)xv;
        hi4[i] = h;
        lo4[i] = (__bf16)(xv - (float)h);
        h8[i] = to_fp8(c[i] * inv);
      }
      long base = (long)row * FPAD + k0;
      *(uint2*)&xhi[base] = *(const uint2*)hi4;
      *(uint2*)&xlo[base] = *(const uint2*)lo4;
      *(unsigned int*)&xhat8[base] = *(const unsigned int*)h8;
    }
  } else if (bid < 16384 + 224) {
    int idx = (bid - 16384) * 256 + threadIdx.x;  // 256*224
    int h = idx / FPAD, k = idx % FPAD;
    float v = 0.f;
    if (k < FIN) v = (h < HD) ? W1l[h * FIN + k] : W1r[(h - HD) * FIN + k];
    __bf16 a = (__bf16)v;
    hi1[idx] = a;
    lo1[idx] = (__bf16)(v - (float)a);
  } else if (bid < 16672) {
    int idx = (bid - 16384 - 224) * 256 + threadIdx.x;  // 128*128
    int h = idx / HD, k = idx % HD;
    float v = (h < OD) ? W2l[h * HD + k] : W2r[(h - OD) * HD + k];
    __bf16 a = (__bf16)v;
    hi2[idx] = a;
    lo2[idx] = (__bf16)(v - (float)a);
  } else if (bid < 16800) {
    // fc1T[j*512+o] = fc1_w[o*64+j]  (write-coalesced)
    int idx = (bid - 16672) * 256 + threadIdx.x;  // 0..32767
    int o = idx & 511, j = idx >> 9;
    fc1t[idx] = fc1w[o * 64 + j];
  } else {
    // fc2T[j*256+o] = fc2_w[o*512+j]  (write-coalesced)
    int idx = (bid - 16800) * 256 + threadIdx.x;  // 0..131071
    int o = idx & 255, j = idx >> 8;
    fc2t[idx] = fc2w[o * 512 + j];
  }
}

// ---------------------------------------------------------------------------
// K1+K2 merged: corr bits (inline mirror transpose) + gemm1.  Sequential
// block split (R19 — interleave measured worse, R21).
// Blocks [0,2304): corr — upper-triangular 128x128 pairs (36/batch), XCD
//   swizzle; R22: DOUBLE-BUFFERED [2][128][CKB] tiles — load(k+1) into regs,
//   MFMA(k), write regs->buf^1, ONE barrier per iter (7 vs 14 barriers;
//   load latency hides under the 48 MFMAs).  Inline mirror via in-register
//   16x16 bit-transpose of ballot masks (bi!=bj only).
// Blocks [2304,3328): gemm1 — C = A @ B^T, 3-term split bf16, K=224, NCOL=2;
//   R16 structure (single-buffer gl16 LDS, 2-barrier K-loop, XOR swizzle).
static constexpr int CKB = 48;  // corr LDS row stride in BYTES (32-wide K chunk)
__global__ __launch_bounds__(256, 3) void corr_gemm1_kernel(
    const unsigned char* __restrict__ xhat8, unsigned short* __restrict__ Abits,
    const __bf16* __restrict__ Ahi, const __bf16* __restrict__ Alo,
    const __bf16* __restrict__ Bhi, const __bf16* __restrict__ Blo,
    float* __restrict__ C) {
  __shared__ __align__(16) char pool[32768];
  int bid = blockIdx.x;
  int t = threadIdx.x;
  int lane = t & 63, wave = t >> 6;
  int wi = (wave >> 1) * 64, wj = (wave & 1) * 64;
  int lr = lane & 15;
  if (bid < 2304) {
    // ================= corr (double-buffered) =================
    unsigned char* sI = (unsigned char*)pool;                  // [2][128][48]
    unsigned char* sJ = (unsigned char*)pool + 2 * 128 * CKB;  // [2][128][48]
    int xcd = bid & 7;
    int m = bid >> 3;
    int b = xcd + ((m & 7) << 3);
    int rem = m >> 3, bi = 0;             // triangular decode -> (bi <= bj)
    while (rem >= 8 - bi) { rem -= 8 - bi; ++bi; }
    int bj = bi + rem;
    int i0 = bi * 128, j0 = bj * 128;
    const unsigned char* Xb = xhat8 + (long)b * NNODE * FPAD;
    int lk8 = (lane >> 4) * 8;            // byte offset of 8-elem fragment
    int strow = t & 127;
    int sbuf = t >> 7;                    // 0 -> I, 1 -> J
    const unsigned char* src = Xb + (long)((sbuf ? j0 : i0) + strow) * FPAD;
    unsigned char* dst0 = (sbuf ? sJ : sI) + strow * CKB;  // buf0 row base
    floatx4 zero = {0.f, 0.f, 0.f, 0.f};
    floatx4 acc[4][4];
#pragma unroll
    for (int i = 0; i < 4; ++i)
#pragma unroll
      for (int j = 0; j < 4; ++j) acc[i][j] = zero;
    // prologue: chunk 0 -> buf 0
    {
      uint4 u0 = *(const uint4*)(src);
      uint4 u1 = *(const uint4*)(src + 16);
      *(uint4*)(dst0)      = u0;
      *(uint4*)(dst0 + 16) = u1;
    }
    __syncthreads();
    for (int kk = 0; kk < 7; ++kk) {
      int cur = kk & 1;
      uint4 u0, u1;
      if (kk < 6) {                       // issue next-chunk loads early
        const unsigned char* s2 = src + (kk + 1) * 32;
        u0 = *(const uint4*)(s2);
        u1 = *(const uint4*)(s2 + 16);
      }
      const unsigned char* rI = sI + cur * (128 * CKB);
      const unsigned char* rJ = sJ + cur * (128 * CKB);
      long long af[4], bf[4];
#pragma unroll
      for (int tt = 0; tt < 4; ++tt) {
        af[tt] = *(const long long*)&rI[(wi + tt * 16 + lr) * CKB + lk8];
        bf[tt] = *(const long long*)&rJ[(wj + tt * 16 + lr) * CKB + lk8];
      }
#pragma unroll
      for (int ti = 0; ti < 4; ++ti)
#pragma unroll
        for (int tj = 0; tj < 4; ++tj)
          acc[ti][tj] = MFMA_FP8(af[ti], bf[tj], acc[ti][tj]);
      if (kk < 6) {                       // write-late into the other buffer
        unsigned char* d = dst0 + (cur ? 0 : 128 * CKB);
        *(uint4*)(d)      = u0;
        *(uint4*)(d + 16) = u1;
        __syncthreads();                  // one barrier per iter (uniform)
      }
    }
#pragma unroll
    for (int ti = 0; ti < 4; ++ti)
#pragma unroll
      for (int tj = 0; tj < 4; ++tj) {
        floatx4 a = acc[ti][tj];
        unsigned long long mr[4];
        mr[0] = __ballot(a[0] > 0.5f);
        mr[1] = __ballot(a[1] > 0.5f);
        mr[2] = __ballot(a[2] > 0.5f);
        mr[3] = __ballot(a[3] > 0.5f);
        if (lane < 16) {
          // upper piece: row = i0+wi+ti*16+lane, 16 cols at j0+wj+tj*16
          unsigned long long mm = mr[lane & 3];
          unsigned short piece = (unsigned short)(mm >> ((lane >> 2) * 16));
          int grow = i0 + wi + ti * 16 + lane;
          int gcol = (j0 + wj + tj * 16) >> 4;
          Abits[((long)b * NNODE + grow) * 64 + gcol] = piece;
          if (bi != bj) {
            // mirror piece: bit tp[tb] = original (row=tb, col=lane) of this
            // 16x16 tile; original bit lives in mr[tb&3] at bit (tb>>2)*16+lane.
            unsigned int tp = 0;
#pragma unroll
            for (int tb = 0; tb < 16; ++tb)
              tp |= (unsigned int)((mr[tb & 3] >> ((tb >> 2) * 16 + lane)) & 1ULL) << tb;
            int grow2 = j0 + wj + tj * 16 + lane;
            int gcol2 = (i0 + wi + ti * 16) >> 4;
            Abits[((long)b * NNODE + grow2) * 64 + gcol2] = (unsigned short)tp;
          }
        }
      }
  } else {
    // ================= gemm1 (K=224, NCOL=2) =================
    constexpr int K = 224;
    constexpr int ldc = 256;
    int gid = bid - 2304;
    int xcd = gid & 7;               // pair (m, col0/1) shares gid mod 8
    int q = gid >> 3;
    int col = q & 1;
    int mrow = (xcd << 6) + (q >> 1);
    __bf16* sAh = (__bf16*)pool;                  // 8192B each
    __bf16* sAl = (__bf16*)(pool + 8192);
    __bf16* sBh = (__bf16*)(pool + 16384);
    __bf16* sBl = (__bf16*)(pool + 24576);
    long row0 = (long)mrow * 128;
    int col0 = col * 128;
    int lk2 = (lane >> 4) * 16;                   // byte offset of K-fragment
    int lk2s = lk2 ^ (((lr >> 1) & 3) << 4);      // swizzled read offset
    // staging: thread t owns LDS (row t>>2, slot t&3); fetch global slot
    // (t&3)^((row>>1)&3) so the linear DMA write lands swizzled data.
    int sr = t >> 2;
    int scb = (((t & 3) ^ ((sr >> 1) & 3)) << 4); // source byte offset in 64B row
    const char* gA0 = (const char*)Ahi + (row0 + sr) * (long)K * 2 + scb;
    const char* gA1 = (const char*)Alo + (row0 + sr) * (long)K * 2 + scb;
    const char* gB0 = (const char*)Bhi + (long)(col0 + sr) * K * 2 + scb;
    const char* gB1 = (const char*)Blo + (long)(col0 + sr) * K * 2 + scb;
    constexpr long rstep = 64L * K * 2;           // +64 rows, bytes
    char* lAh = (char*)sAh + (wave << 10);        // wave-uniform LDS bases
    char* lAl = (char*)sAl + (wave << 10);
    char* lBh = (char*)sBh + (wave << 10);
    char* lBl = (char*)sBl + (wave << 10);
    floatx4 zero = {0.f, 0.f, 0.f, 0.f};
    floatx4 acc[4][4];
#pragma unroll
    for (int i = 0; i < 4; ++i)
#pragma unroll
      for (int j = 0; j < 4; ++j) acc[i][j] = zero;
    for (int kk = 0; kk < (K >> 5); ++kk) {
      __syncthreads();                            // prev compute done
      gl16(gA0, lAh); gl16(gA0 + rstep, lAh + 4096);
      gl16(gA1, lAl); gl16(gA1 + rstep, lAl + 4096);
      gl16(gB0, lBh); gl16(gB0 + rstep, lBh + 4096);
      gl16(gB1, lBl); gl16(gB1 + rstep, lBl + 4096);
      gA0 += 64; gA1 += 64; gB0 += 64; gB1 += 64; // next 32-col K chunk
      __syncthreads();                            // vmcnt drained -> tiles ready
      bf16x8 bh[4], bl[4];
#pragma unroll
      for (int tj = 0; tj < 4; ++tj) {
        bh[tj] = *(const bf16x8*)((const char*)sBh + (wj + tj * 16 + lr) * 64 + lk2s);
        bl[tj] = *(const bf16x8*)((const char*)sBl + (wj + tj * 16 + lr) * 64 + lk2s);
      }
#pragma unroll
      for (int ti = 0; ti < 4; ++ti) {
        bf16x8 ah = *(const bf16x8*)((const char*)sAh + (wi + ti * 16 + lr) * 64 + lk2s);
        bf16x8 al = *(const bf16x8*)((const char*)sAl + (wi + ti * 16 + lr) * 64 + lk2s);
#pragma unroll
        for (int tj = 0; tj < 4; ++tj) acc[ti][tj] = MFMA_BF16(ah, bh[tj], acc[ti][tj]);
#pragma unroll
        for (int tj = 0; tj < 4; ++tj) acc[ti][tj] = MFMA_BF16(ah, bl[tj], acc[ti][tj]);
#pragma unroll
        for (int tj = 0; tj < 4; ++tj) acc[ti][tj] = MFMA_BF16(al, bh[tj], acc[ti][tj]);
      }
    }
#pragma unroll
    for (int ti = 0; ti < 4; ++ti)
#pragma unroll
      for (int tj = 0; tj < 4; ++tj)
#pragma unroll
        for (int rr = 0; rr < 4; ++rr) {
          long grow = row0 + wi + ti * 16 + (lane >> 4) * 4 + rr;
          int gcol = col0 + wj + tj * 16 + (lane & 15);
          C[grow * ldc + gcol] = acc[ti][tj][rr];
        }
  }
}

// ---------------------------------------------------------------------------
// K7: gemm2 — C = A @ B^T, 3-term split bf16, K=128, NCOL=1 (R16 structure).
template <int K, int NCOL>
__global__ __launch_bounds__(256, 3) void gemm_split_kernel(
    const __bf16* __restrict__ Ahi, const __bf16* __restrict__ Alo,
    const __bf16* __restrict__ Bhi, const __bf16* __restrict__ Blo,
    float* __restrict__ C) {
  constexpr int ldc = NCOL * 128;
  int bid = blockIdx.x;
  int mrow, col;
  if (NCOL == 2) {
    int xcd = bid & 7;
    int q = bid >> 3;
    col = q & 1;
    mrow = (xcd << 6) + (q >> 1);
  } else {
    mrow = bid;
    col = 0;
  }
  __shared__ __align__(16) __bf16 sAh[128 * 32];
  __shared__ __align__(16) __bf16 sAl[128 * 32];
  __shared__ __align__(16) __bf16 sBh[128 * 32];
  __shared__ __align__(16) __bf16 sBl[128 * 32];
  long row0 = (long)mrow * 128;
  int col0 = col * 128;
  int t = threadIdx.x;
  int lane = t & 63, wave = t >> 6;
  int wi = (wave >> 1) * 64, wj = (wave & 1) * 64;
  int lr = lane & 15, lk2 = (lane >> 4) * 16;   // byte offset of K-fragment
  int lk2s = lk2 ^ (((lr >> 1) & 3) << 4);      // swizzled read offset
  int sr = t >> 2;
  int scb = (((t & 3) ^ ((sr >> 1) & 3)) << 4); // source byte offset in 64B row
  const char* gA0 = (const char*)Ahi + (row0 + sr) * (long)K * 2 + scb;
  const char* gA1 = (const char*)Alo + (row0 + sr) * (long)K * 2 + scb;
  const char* gB0 = (const char*)Bhi + (long)(col0 + sr) * K * 2 + scb;
  const char* gB1 = (const char*)Blo + (long)(col0 + sr) * K * 2 + scb;
  constexpr long rstep = 64L * K * 2;           // +64 rows, bytes
  char* lAh = (char*)sAh + (wave << 10);        // wave-uniform LDS bases
  char* lAl = (char*)sAl + (wave << 10);
  char* lBh = (char*)sBh + (wave << 10);
  char* lBl = (char*)sBl + (wave << 10);
  floatx4 zero = {0.f, 0.f, 0.f, 0.f};
  floatx4 acc[4][4];
#pragma unroll
  for (int i = 0; i < 4; ++i)
#pragma unroll
    for (int j = 0; j < 4; ++j) acc[i][j] = zero;
  for (int kk = 0; kk < (K >> 5); ++kk) {
    __syncthreads();                            // prev compute done
    gl16(gA0, lAh); gl16(gA0 + rstep, lAh + 4096);
    gl16(gA1, lAl); gl16(gA1 + rstep, lAl + 4096);
    gl16(gB0, lBh); gl16(gB0 + rstep, lBh + 4096);
    gl16(gB1, lBl); gl16(gB1 + rstep, lBl + 4096);
    gA0 += 64; gA1 += 64; gB0 += 64; gB1 += 64; // next 32-col K chunk
    __syncthreads();                            // vmcnt drained -> tiles ready
    bf16x8 bh[4], bl[4];
#pragma unroll
    for (int tj = 0; tj < 4; ++tj) {
      bh[tj] = *(const bf16x8*)((const char*)sBh + (wj + tj * 16 + lr) * 64 + lk2s);
      bl[tj] = *(const bf16x8*)((const char*)sBl + (wj + tj * 16 + lr) * 64 + lk2s);
    }
#pragma unroll
    for (int ti = 0; ti < 4; ++ti) {
      bf16x8 ah = *(const bf16x8*)((const char*)sAh + (wi + ti * 16 + lr) * 64 + lk2s);
      bf16x8 al = *(const bf16x8*)((const char*)sAl + (wi + ti * 16 + lr) * 64 + lk2s);
#pragma unroll
      for (int tj = 0; tj < 4; ++tj) acc[ti][tj] = MFMA_BF16(ah, bh[tj], acc[ti][tj]);
#pragma unroll
      for (int tj = 0; tj < 4; ++tj) acc[ti][tj] = MFMA_BF16(ah, bl[tj], acc[ti][tj]);
#pragma unroll
      for (int tj = 0; tj < 4; ++tj) acc[ti][tj] = MFMA_BF16(al, bh[tj], acc[ti][tj]);
    }
  }
#pragma unroll
  for (int ti = 0; ti < 4; ++ti)
#pragma unroll
    for (int tj = 0; tj < 4; ++tj)
#pragma unroll
      for (int rr = 0; rr < 4; ++rr) {
        long grow = row0 + wi + ti * 16 + (lane >> 4) * 4 + rr;
        int gcol = col0 + wj + tj * 16 + (lane & 15);
        C[grow * ldc + gcol] = acc[ti][tj][rr];
      }
}

// ---------------------------------------------------------------------------
// K3: sage1, float4 form (R12).  8 nodes per 256-thread block; 32 lanes per
// node, each lane owns 4 consecutive h (float4 loads of YR1).
__global__ __launch_bounds__(256) void sage1_kernel(
    const unsigned int* __restrict__ Abits32, const float* __restrict__ YR1,
    const float* __restrict__ b1l, const float* __restrict__ Wrel,
    const float* __restrict__ Wroot, float* __restrict__ x1,
    float* __restrict__ p1, float* __restrict__ q1) {
  int g = threadIdx.x >> 5;          // 8 node-groups of 32 lanes
  int lane = threadIdx.x & 31;
  int node = blockIdx.x * 8 + g;     // b*1024+n
  int b = node >> 10, nloc = node & 1023;
  __shared__ int list[8][1024];
  __shared__ int s_deg[8];
  {
    unsigned int word = Abits32[(long)node * 32 + lane];
    int cnt = __popc(word);
    int off = cnt;
#pragma unroll
    for (int o = 1; o < 32; o <<= 1) {
      int v = __shfl_up(off, o, 32);
      if (lane >= o) off += v;
    }
    off -= cnt;  // exclusive prefix (ascending word order -> ordered list)
    if (lane == 31) s_deg[g] = off + cnt;
    int basei = lane * 32;
    while (word) {
      int t = __ffs(word) - 1;
      word &= word - 1;
      list[g][off++] = basei + t;
    }
  }
  __syncthreads();
  int deg = s_deg[g];
  const float4* Y4 = (const float4*)(YR1 + (long)(b << 10) * 256);  // 64 f4/row
  float4 a4 = {0.f, 0.f, 0.f, 0.f};
  for (int d = 0; d < deg; ++d) {
    float4 y = Y4[(long)list[g][d] * 64 + lane];
    a4.x += y.x; a4.y += y.y; a4.z += y.z; a4.w += y.w;
  }
  float4 R = Y4[(long)nloc * 64 + 32 + lane];
  float inv = 1.f / (float)(deg < 1 ? 1 : deg);
  float4 bl = ((const float4*)b1l)[lane];
  float4 v;
  v.x = fmaxf(a4.x * inv + bl.x + R.x, 0.f);
  v.y = fmaxf(a4.y * inv + bl.y + R.y, 0.f);
  v.z = fmaxf(a4.z * inv + bl.z + R.z, 0.f);
  v.w = fmaxf(a4.w * inv + bl.w + R.w, 0.f);
  ((float4*)x1)[(long)node * 32 + lane] = v;
  float4 wr = ((const float4*)Wrel)[lane];
  float4 wq = ((const float4*)Wroot)[lane];
  float pv = v.x * wr.x + v.y * wr.y + v.z * wr.z + v.w * wr.w;
  float qv = v.x * wq.x + v.y * wq.y + v.z * wq.z + v.w * wq.w;
#pragma unroll
  for (int o = 16; o; o >>= 1) {
    pv += __shfl_xor(pv, o, 32);
    qv += __shfl_xor(qv, o, 32);
  }
  if (lane == 0) { p1[node] = pv; q1[node] = qv; }
}

// ---------------------------------------------------------------------------
// K4+K5 fused: per-batch score (thread-per-row, sparse while-gather — cheap
// since deg~1 on this data) + radix top-k selection.
__global__ void scoretopk_kernel(const unsigned int* __restrict__ bits32,
                                 const float* __restrict__ p,
                                 const float* __restrict__ q,
                                 const float* __restrict__ brel,
                                 int* __restrict__ idx_out,
                                 float* __restrict__ gate_out,
                                 int nwords, int rpb_shift, int k) {
  int b = blockIdx.x, tid = threadIdx.x;
  int row = (b << rpb_shift) + tid;
  const unsigned int* wptr = bits32 + (long)row * nwords;
  const float* pb = p + ((long)b << rpb_shift);
  float s = q[row] + brel[0];
  for (int w = 0; w < nwords; ++w) {
    unsigned int word = wptr[w];
    while (word) {
      int t = __ffs(word) - 1;
      word &= word - 1;
      s += pb[w * 32 + t];
    }
  }
  unsigned int fb = __float_as_uint(s);
  unsigned int key = (fb & 0x80000000u) ? ~fb : (fb | 0x80000000u);
  __shared__ int hist[256];
  __shared__ unsigned int sh_prefix;
  __shared__ int sh_target, cnt_gt, cnt_eq, outpos;
  if (tid == 0) { sh_prefix = 0; sh_target = k; cnt_gt = 0; cnt_eq = 0; outpos = 0; }
  for (int shift = 24; shift >= 0; shift -= 8) {
    if (tid < 256) hist[tid] = 0;
    __syncthreads();
    unsigned int prefix = sh_prefix;
    bool inset = (shift == 24) || ((key >> (shift + 8)) == (prefix >> (shift + 8)));
    if (inset) atomicAdd(&hist[(key >> shift) & 255], 1);
    __syncthreads();
    if (tid < 64) {
      int lane = tid;
      int bb0 = hist[255 - 4 * lane];
      int bb1 = hist[254 - 4 * lane];
      int bb2 = hist[253 - 4 * lane];
      int bb3 = hist[252 - 4 * lane];
      int c0 = bb0, c1 = c0 + bb1, c2 = c1 + bb2, c3 = c2 + bb3;
      int incl = c3;
#pragma unroll
      for (int o = 1; o < 64; o <<= 1) {
        int v = __shfl_up(incl, o);
        if (lane >= o) incl += v;
      }
      int excl = incl - c3;
      int target = sh_target;  // read before any lane writes (lockstep)
      int cum[4] = {excl + c0, excl + c1, excl + c2, excl + c3};
      int prev = excl;
#pragma unroll
      for (int i = 0; i < 4; ++i) {
        if (cum[i] >= target && prev < target) {
          int bin = 255 - (4 * lane + i);
          sh_prefix = prefix | ((unsigned int)bin << shift);
          sh_target = target - prev;
        }
        prev = cum[i];
      }
    }
    __syncthreads();
  }
  unsigned int T = sh_prefix;
  if (key > T) atomicAdd(&cnt_gt, 1);
  __syncthreads();
  int E = k - cnt_gt;
  bool sel = (key > T);
  if (!sel && key == T) sel = (atomicAdd(&cnt_eq, 1) < E);
  if (sel) {
    int posn = atomicAdd(&outpos, 1);
    idx_out[b * k + posn] = tid;
    gate_out[b * k + posn] = tanhf(s);
  }
}

// K6: fused gather: x1 rows * tanh gate -> split bf16, and A1 bit gather.
__global__ __launch_bounds__(256) void gather_kernel(
    const float* __restrict__ x1, const int* __restrict__ idx,
    const float* __restrict__ gate, __bf16* __restrict__ ghi,
    __bf16* __restrict__ glo, const unsigned int* __restrict__ Abits32,
    unsigned long long* __restrict__ A1bits) {
  int bid = blockIdx.x;
  if (bid < 16384) {
    long e = (long)bid * 256 + threadIdx.x;  // B*512*128
    int h = (int)(e & 127);
    int i = (int)((e >> 7) & 511);
    int b = (int)(e >> 16);
    int srow = idx[(b << 9) + i];
    float v = x1[((long)(b << 10) + srow) * 128 + h] * gate[(b << 9) + i];
    __bf16 a = (__bf16)v;
    ghi[e] = a;
    glo[e] = (__bf16)(v - (float)a);
  } else {
    int gi = (bid - 16384) * 4 + (threadIdx.x >> 6);  // b*512+i
    int lane = threadIdx.x & 63;
    int b = gi >> 9;
    int srow = idx[gi];
    const unsigned int* src = Abits32 + ((long)(b << 10) + srow) * 32;
    const int* idxb = idx + (b << 9);
#pragma unroll
    for (int t = 0; t < 8; ++t) {
      int cj = idxb[t * 64 + lane];
      int bit = (src[cj >> 5] >> (cj & 31)) & 1;
      unsigned long long m = __ballot(bit);
      if (lane == 0) A1bits[(long)gi * 8 + t] = m;
    }
  }
}

// K8: sage2, float4 form (R12).  16 nodes per 256-thread block; 16 lanes per
// node, each lane owns 4 consecutive h.
__global__ __launch_bounds__(256) void sage2_kernel(
    const unsigned int* __restrict__ A1b32, const float* __restrict__ YR2,
    const float* __restrict__ b2l, const float* __restrict__ Wrel,
    const float* __restrict__ Wroot, float* __restrict__ x2,
    float* __restrict__ p2, float* __restrict__ q2) {
  int g = threadIdx.x >> 4;          // 16 node-groups of 16 lanes
  int lane = threadIdx.x & 15;
  int row = blockIdx.x * 16 + g;     // b*512+i
  int b = row >> 9, iloc = row & 511;
  __shared__ int list[16][512];
  __shared__ int s_deg[16];
  {
    unsigned int word = A1b32[(long)row * 16 + lane];
    int cnt = __popc(word);
    int off = cnt;
#pragma unroll
    for (int o = 1; o < 16; o <<= 1) {
      int v = __shfl_up(off, o, 16);
      if (lane >= o) off += v;
    }
    off -= cnt;
    if (lane == 15) s_deg[g] = off + cnt;
    int basei = lane * 32;
    while (word) {
      int t = __ffs(word) - 1;
      word &= word - 1;
      list[g][off++] = basei + t;
    }
  }
  __syncthreads();
  int deg = s_deg[g];
  const float4* Y4 = (const float4*)(YR2 + (long)(b << 9) * 128);  // 32 f4/row
  float4 a4 = {0.f, 0.f, 0.f, 0.f};
  for (int d = 0; d < deg; ++d) {
    float4 y = Y4[(long)list[g][d] * 32 + lane];
    a4.x += y.x; a4.y += y.y; a4.z += y.z; a4.w += y.w;
  }
  float4 R = Y4[(long)iloc * 32 + 16 + lane];
  float inv = 1.f / (float)(deg < 1 ? 1 : deg);
  float4 bl = ((const float4*)b2l)[lane];
  float4 v;
  v.x = fmaxf(a4.x * inv + bl.x + R.x, 0.f);
  v.y = fmaxf(a4.y * inv + bl.y + R.y, 0.f);
  v.z = fmaxf(a4.z * inv + bl.z + R.z, 0.f);
  v.w = fmaxf(a4.w * inv + bl.w + R.w, 0.f);
  ((float4*)x2)[(long)row * 16 + lane] = v;
  float4 wr = ((const float4*)Wrel)[lane];
  float4 wq = ((const float4*)Wroot)[lane];
  float pv = v.x * wr.x + v.y * wr.y + v.z * wr.z + v.w * wr.w;
  float qv = v.x * wq.x + v.y * wq.y + v.z * wq.z + v.w * wq.w;
#pragma unroll
  for (int o = 8; o; o >>= 1) {
    pv += __shfl_xor(pv, o, 16);
    qv += __shfl_xor(qv, o, 16);
  }
  if (lane == 0) { p2[row] = pv; q2[row] = qv; }
}

// ---------------------------------------------------------------------------
// K9+K10+K11 fused: per-batch score2 + topk2 (idx/gate in LDS) + MLP head.
// Score = sparse while-gather (R16 form); MLP per-thread with TRANSPOSED
// weights (fc1T[j][o], fc2T[j][o]) -> coalesced lane access (R18).
__global__ __launch_bounds__(512) void scoretopk_head_kernel(
    const unsigned int* __restrict__ A1b32, const float* __restrict__ p2,
    const float* __restrict__ q2, const float* __restrict__ brel,
    const float* __restrict__ x2, const float* __restrict__ fc1t,
    const float* __restrict__ fc1_b, const float* __restrict__ g1,
    const float* __restrict__ bb1, const float* __restrict__ m1,
    const float* __restrict__ v1, const float* __restrict__ fc2t,
    const float* __restrict__ fc2_b, const float* __restrict__ g2,
    const float* __restrict__ bb2, const float* __restrict__ m2,
    const float* __restrict__ v2, const float* __restrict__ fc3_w,
    const float* __restrict__ fc3_b, float* __restrict__ out) {
  int b = blockIdx.x, tid = threadIdx.x;
  // ---- score (thread-per-row, 512 rows, 16 words; sparse gather) ----
  int row = (b << 9) + tid;
  const unsigned int* wptr = A1b32 + (long)row * 16;
  const float* pb = p2 + ((long)b << 9);
  float s = q2[row] + brel[0];
  for (int w = 0; w < 16; ++w) {
    unsigned int word = wptr[w];
    while (word) {
      int t = __ffs(word) - 1;
      word &= word - 1;
      s += pb[w * 32 + t];
    }
  }
  // ---- top-256 radix select into LDS ----
  constexpr int k = KP2;
  unsigned int fb = __float_as_uint(s);
  unsigned int key = (fb & 0x80000000u) ? ~fb : (fb | 0x80000000u);
  __shared__ int hist[256];
  __shared__ int idx2s[256];
  __shared__ float gate2s[256];
  __shared__ unsigned int sh_prefix;
  __shared__ int sh_target, cnt_gt, cnt_eq, outpos;
  if (tid == 0) { sh_prefix = 0; sh_target = k; cnt_gt = 0; cnt_eq = 0; outpos = 0; }
  for (int shift = 24; shift >= 0; shift -= 8) {
    if (tid < 256) hist[tid] = 0;
    __syncthreads();
    unsigned int prefix = sh_prefix;
    bool inset = (shift == 24) || ((key >> (shift + 8)) == (prefix >> (shift + 8)));
    if (inset) atomicAdd(&hist[(key >> shift) & 255], 1);
    __syncthreads();
    if (tid < 64) {
      int lane = tid;
      int bb0 = hist[255 - 4 * lane];
      int bb1 = hist[254 - 4 * lane];
      int bb2 = hist[253 - 4 * lane];
      int bb3 = hist[252 - 4 * lane];
      int c0 = bb0, c1 = c0 + bb1, c2 = c1 + bb2, c3 = c2 + bb3;
      int incl = c3;
#pragma unroll
      for (int o = 1; o < 64; o <<= 1) {
        int v = __shfl_up(incl, o);
        if (lane >= o) incl += v;
      }
      int excl = incl - c3;
      int target = sh_target;
      int cum[4] = {excl + c0, excl + c1, excl + c2, excl + c3};
      int prev = excl;
#pragma unroll
      for (int i = 0; i < 4; ++i) {
        if (cum[i] >= target && prev < target) {
          int bin = 255 - (4 * lane + i);
          sh_prefix = prefix | ((unsigned int)bin << shift);
          sh_target = target - prev;
        }
        prev = cum[i];
      }
    }
    __syncthreads();
  }
  unsigned int T = sh_prefix;
  if (key > T) atomicAdd(&cnt_gt, 1);
  __syncthreads();
  int E = k - cnt_gt;
  bool sel = (key > T);
  if (!sel && key == T) sel = (atomicAdd(&cnt_eq, 1) < E);
  if (sel) {
    int posn = atomicAdd(&outpos, 1);
    idx2s[posn] = tid;
    gate2s[posn] = tanhf(s);
  }
  __syncthreads();
  // ---- head: mean pool over selected + MLP (transposed, coalesced) ----
  __shared__ float part[8][64];
  __shared__ float pooled[64];
  __shared__ float h1[512];
  __shared__ float h2[256];
  __shared__ float zz[2];
  int h = tid & 63, grp = tid >> 6;
  float sp = 0.f;
  for (int i = grp * 32; i < grp * 32 + 32; ++i) {
    int si = idx2s[i];
    sp += x2[((long)(b << 9) + si) * 64 + h] * gate2s[i];
  }
  part[grp][h] = sp;
  __syncthreads();
  if (tid < 64) {
    float t = 0.f;
#pragma unroll
    for (int g = 0; g < 8; ++g) t += part[g][tid];
    pooled[tid] = t * (1.f / 256.f);
  }
  __syncthreads();
  {
    // fc1: out o = tid (512); fc1T[j*512+o] -> lane-consecutive (coalesced)
    float z = fc1_b[tid];
#pragma unroll 8
    for (int j = 0; j < 64; ++j) z += pooled[j] * fc1t[j * 512 + tid];
    z = fmaxf(z, 0.f);
    h1[tid] = g1[tid] * (z - m1[tid]) * rsqrtf(v1[tid] + 1e-5f) + bb1[tid];
  }
  __syncthreads();
  if (tid < 256) {
    // fc2: out o = tid (256); fc2T[j*256+o] -> lane-consecutive (coalesced)
    float z = fc2_b[tid];
#pragma unroll 8
    for (int j = 0; j < 512; ++j) z += h1[j] * fc2t[j * 256 + tid];
    z = fmaxf(z, 0.f);
    h2[tid] = g2[tid] * (z - m2[tid]) * rsqrtf(v2[tid] + 1e-5f) + bb2[tid];
  }
  __syncthreads();
  if (tid < 2) {
    float z = fc3_b[tid];
    for (int j = 0; j < 256; ++j) z += h2[j] * fc3_w[tid * 256 + j];
    zz[tid] = z;
  }
  __syncthreads();
  if (tid == 0) {
    float mx = fmaxf(zz[0], zz[1]);
    float e0 = expf(zz[0] - mx), e1 = expf(zz[1] - mx);
    float inv = 1.f / (e0 + e1);
    out[b * 2 + 0] = e0 * inv;
    out[b * 2 + 1] = e1 * inv;
  }
}

// ---------------------------------------------------------------------------
extern "C" void kernel_launch(void* const* d_in, const int* in_sizes, int n_in,
                              void* d_out, int out_size, void* d_ws, size_t ws_size,
                              hipStream_t stream) {
  (void)in_sizes; (void)n_in; (void)out_size; (void)ws_size;
  const float* input   = (const float*)d_in[0];
  const float* W1l     = (const float*)d_in[1];
  const float* b1l     = (const float*)d_in[2];
  const float* W1r     = (const float*)d_in[3];
  const float* Wp1_rel = (const float*)d_in[4];
  const float* bp1_rel = (const float*)d_in[5];
  const float* Wp1_root= (const float*)d_in[6];
  const float* W2l     = (const float*)d_in[7];
  const float* b2l     = (const float*)d_in[8];
  const float* W2r     = (const float*)d_in[9];
  const float* Wp2_rel = (const float*)d_in[10];
  const float* bp2_rel = (const float*)d_in[11];
  const float* Wp2_root= (const float*)d_in[12];
  const float* fc1_w   = (const float*)d_in[13];
  const float* fc1_b   = (const float*)d_in[14];
  const float* bn1_g   = (const float*)d_in[15];
  const float* bn1_b   = (const float*)d_in[16];
  const float* bn1_m   = (const float*)d_in[17];
  const float* bn1_v   = (const float*)d_in[18];
  const float* fc2_w   = (const float*)d_in[19];
  const float* fc2_b   = (const float*)d_in[20];
  const float* bn2_g   = (const float*)d_in[21];
  const float* bn2_b   = (const float*)d_in[22];
  const float* bn2_m   = (const float*)d_in[23];
  const float* bn2_v   = (const float*)d_in[24];
  const float* fc3_w   = (const float*)d_in[25];
  const float* fc3_b   = (const float*)d_in[26];

  char* ws = (char*)d_ws;
  __bf16* xhi   = (__bf16*)(ws + OFF_XHI);
  __bf16* xlo   = (__bf16*)(ws + OFF_XLO);
  unsigned char* xhat8 = (unsigned char*)(ws + OFF_XHAT);
  unsigned short* Abits = (unsigned short*)(ws + OFF_ABITS);
  const unsigned int* Abits32 = (const unsigned int*)(ws + OFF_ABITS);
  float* YR1    = (float*)(ws + OFF_YR1);
  float* x1     = (float*)(ws + OFF_X1);
  float* p1     = (float*)(ws + OFF_P1);
  float* q1     = (float*)(ws + OFF_Q1);
  int*   idx1   = (int*)(ws + OFF_IDX1);
  float* gate1  = (float*)(ws + OFF_GATE1);
  float* p2     = (float*)(ws + OFF_P2);
  float* q2     = (float*)(ws + OFF_Q2);
  __bf16* w1hi  = (__bf16*)(ws + OFF_W1HI);
  __bf16* w1lo  = (__bf16*)(ws + OFF_W1LO);
  __bf16* w2hi  = (__bf16*)(ws + OFF_W2HI);
  __bf16* w2lo  = (__bf16*)(ws + OFF_W2LO);
  float* fc1t   = (float*)(ws + OFF_FC1T);
  float* fc2t   = (float*)(ws + OFF_FC2T);
  __bf16* ghi   = (__bf16*)(ws + OFF_GHI);
  __bf16* glo   = (__bf16*)(ws + OFF_GLO);
  unsigned long long* A1bits = (unsigned long long*)(ws + OFF_A1B);
  const unsigned int* A1b32  = (const unsigned int*)(ws + OFF_A1B);
  float* YR2    = (float*)(ws + OFF_YR2);
  float* x2     = (float*)(ws + OFF_X2);
  float* out    = (float*)d_out;

  prep_pack_kernel<<<17312, 256, 0, stream>>>(input, xhi, xlo, xhat8,
                                              W1l, W1r, w1hi, w1lo,
                                              W2l, W2r, w2hi, w2lo,
                                              fc1_w, fc1t, fc2_w, fc2t);
  // merged (sequential split): 2304 corr blocks (dbuf staging + inline
  // mirror) + 1024 gemm1 blocks
  corr_gemm1_kernel<<<3328, 256, 0, stream>>>(xhat8, Abits,
                                              xhi, xlo, w1hi, w1lo, YR1);
  sage1_kernel<<<8192, 256, 0, stream>>>(Abits32, YR1, b1l, Wp1_rel, Wp1_root, x1, p1, q1);
  scoretopk_kernel<<<64, 1024, 0, stream>>>(Abits32, p1, q1, bp1_rel, idx1, gate1,
                                            32, 10, KP1);
  gather_kernel<<<24576, 256, 0, stream>>>(x1, idx1, gate1, ghi, glo, Abits32, A1bits);
  gemm_split_kernel<128, 1><<<256, 256, 0, stream>>>(
      ghi, glo, w2hi, w2lo, YR2);
  sage2_kernel<<<2048, 256, 0, stream>>>(A1b32, YR2, b2l, Wp2_rel, Wp2_root, x2, p2, q2);
  scoretopk_head_kernel<<<64, 512, 0, stream>>>(A1b32, p2, q2, bp2_rel, x2,
                                                fc1t, fc1_b, bn1_g, bn1_b, bn1_m, bn1_v,
                                                fc2t, fc2_b, bn2_g, bn2_b, bn2_m, bn2_v,
                                                fc3_w, fc3_b, out);
}